// Round 3
// baseline (289.587 us; speedup 1.0000x reference)
//
#include <hip/hip_runtime.h>

#define BSZ   8
#define NQ    1000
#define DM    256
#define MROWS (BSZ*NQ)
#define TOPK  10

// ---------------- IoU + attn_mask + top-k candidate selection ----------------
// One block per (b,i) row. Computes IoU vs all j (f32, contract-off so the
// >=0.5 comparisons match the numpy f32 reference bit-exactly), writes the
// attn_mask row (as f32 0/1), filters overlaps >= 0.5 into an LDS list, then
// one thread does exact top-10 under (value desc, index asc) ordering — the
// same order as stable argsort(-overlaps).
__global__ __launch_bounds__(256) void iou_topk_k(
    const float* __restrict__ boxes, const float* __restrict__ seed,
    float* __restrict__ attn, int* __restrict__ cnt, int* __restrict__ inc0,
    int* __restrict__ idxs)
{
#pragma clang fp contract(off)
    __shared__ float sv[NQ];
    __shared__ int   sj[NQ];
    __shared__ int   scount;
    const int t   = threadIdx.x;
    const int row = blockIdx.x;          // b*NQ + i
    const int b   = row / NQ;
    if (t == 0) scount = 0;

    const float* bi = boxes + (size_t)row * 4;
    const float icx = bi[0], icy = bi[1], iw = bi[2], ih = bi[3];
    const float ix0 = icx - 0.5f*iw, iy0 = icy - 0.5f*ih;
    const float ix1 = icx + 0.5f*iw, iy1 = icy + 0.5f*ih;
    const float area_i = (ix1-ix0)*(iy1-iy0);
    const float neg_i  = 1.f - seed[row];
    __syncthreads();

    float* arow = attn + (size_t)row * NQ;
    for (int j = t; j < NQ; j += 256) {
        const float* bj = boxes + (size_t)(b*NQ + j) * 4;
        const float cx = bj[0], cy = bj[1], w = bj[2], h = bj[3];
        const float x0 = cx - 0.5f*w, y0 = cy - 0.5f*h;
        const float x1 = cx + 0.5f*w, y1 = cy + 0.5f*h;
        const float area_j = (x1-x0)*(y1-y0);
        const float ltx = fmaxf(ix0, x0), lty = fmaxf(iy0, y0);
        const float rbx = fminf(ix1, x1), rby = fminf(iy1, y1);
        const float wx = fmaxf(rbx-ltx, 0.f), wy = fmaxf(rby-lty, 0.f);
        const float inter = wx*wy;
        const float uni = (area_i + area_j) - inter;
        const float iou = inter / uni;
        arow[j] = (iou >= 0.5f) ? 1.0f : 0.0f;
        // overlaps = (iou * seed_j) * neg_i — exact since seed/neg in {0,1}
        const float ov = (iou * seed[b*NQ + j]) * neg_i;
        if (ov >= 0.5f) {
            const int p = atomicAdd(&scount, 1);
            if (p < NQ) { sv[p] = ov; sj[p] = j; }
        }
    }
    __syncthreads();

    if (t == 0) {
        const int n = scount;
        inc0[row] = (n < TOPK) ? 1 : 0;   // some selected slot has mk==0 -> max includes 0
        if (n <= TOPK) {
            cnt[row] = n;
            for (int k = 0; k < n; ++k) idxs[row*TOPK + k] = b*NQ + sj[k];
        } else {
            // exact top-10 under (value desc, index asc) — matches stable argsort
            float bv[TOPK]; int bj[TOPK];
            #pragma unroll
            for (int k = 0; k < TOPK; ++k) { bv[k] = -1.f; bj[k] = 0x7fffffff; }
            for (int e = 0; e < n; ++e) {
                const float v = sv[e]; const int j = sj[e];
                int w = 0;
                #pragma unroll
                for (int k = 1; k < TOPK; ++k)
                    if (bv[k] < bv[w] || (bv[k] == bv[w] && bj[k] > bj[w])) w = k;
                if (v > bv[w] || (v == bv[w] && j < bj[w])) { bv[w] = v; bj[w] = j; }
            }
            cnt[row] = TOPK;
            for (int k = 0; k < TOPK; ++k) idxs[row*TOPK + k] = b*NQ + bj[k];
        }
    }
}

// ---------------- generic GEMM: C[M,256] = act(A[M,256] @ W + bias) ----------
// 16 rows per block, thread t = output column. A staged in LDS, W read
// coalesced (f32), float4 LDS broadcast reads in the k-loop.
template<int RELU>
__global__ __launch_bounds__(256) void gemm_k(
    const float* __restrict__ A, const float* __restrict__ W,
    const float* __restrict__ bias, float* __restrict__ C)
{
    __shared__ __align__(16) float As[16][DM];
    const int t  = threadIdx.x;
    const int r0 = blockIdx.x * 16;
    for (int e = t; e < 16*DM; e += 256)
        As[e >> 8][e & 255] = A[(size_t)r0*DM + e];
    __syncthreads();
    float acc[16];
    #pragma unroll
    for (int r = 0; r < 16; ++r) acc[r] = 0.f;
    for (int k = 0; k < DM; k += 4) {
        const float w0 = W[(k+0)*DM + t];
        const float w1 = W[(k+1)*DM + t];
        const float w2 = W[(k+2)*DM + t];
        const float w3 = W[(k+3)*DM + t];
        #pragma unroll
        for (int r = 0; r < 16; ++r) {
            const float4 a = *(const float4*)&As[r][k];
            acc[r] += a.x*w0 + a.y*w1 + a.z*w2 + a.w*w3;
        }
    }
    const float bb = bias ? bias[t] : 0.f;
    #pragma unroll
    for (int r = 0; r < 16; ++r) {
        float v = acc[r] + bb;
        if (RELU) v = fmaxf(v, 0.f);
        C[(size_t)(r0 + r)*DM + t] = v;
    }
}

// ---------------- LayerNorm: one wave per row ----------------
__global__ __launch_bounds__(256) void ln_k(
    const float* __restrict__ Y, const float* __restrict__ g,
    const float* __restrict__ be, float* __restrict__ ID)
{
    const int wave = threadIdx.x >> 6;
    const int lane = threadIdx.x & 63;
    const int row  = blockIdx.x * 4 + wave;
    const float* y = Y + (size_t)row * DM;
    float x[4];
    #pragma unroll
    for (int i = 0; i < 4; ++i) x[i] = y[lane + 64*i];
    float s = x[0]+x[1]+x[2]+x[3];
    float q = x[0]*x[0]+x[1]*x[1]+x[2]*x[2]+x[3]*x[3];
    #pragma unroll
    for (int off = 32; off; off >>= 1) {
        s += __shfl_down(s, off, 64);
        q += __shfl_down(q, off, 64);
    }
    s = __shfl(s, 0, 64);
    q = __shfl(q, 0, 64);
    const float m   = s * (1.f/DM);
    const float v   = q * (1.f/DM) - m*m;
    const float inv = rsqrtf(v + 1e-5f);
    float* o = ID + (size_t)row * DM;
    #pragma unroll
    for (int i = 0; i < 4; ++i) {
        const int c = lane + 64*i;
        o[c] = (x[i]-m)*inv*g[c] + be[c];
    }
}

// ---------------- per-pair feature + masked max ----------------
// One block per row. For each active neighbor j:
//   u = relu(P_i - P_j + b3); feature = u @ W4 + b4; cur = max(cur, feature)
// Rows with count < TOPK have mk==0 slots contributing exactly 0 to the max.
__global__ __launch_bounds__(256) void pairs_k(
    const float* __restrict__ P, const float* __restrict__ b3,
    const float* __restrict__ W4, const float* __restrict__ b4,
    const int* __restrict__ cnt, const int* __restrict__ inc0,
    const int* __restrict__ idxs, float* __restrict__ CMAX)
{
    __shared__ __align__(16) float u[DM];
    const int t   = threadIdx.x;
    const int row = blockIdx.x;
    int n = cnt[row];
    n = (n < 0) ? 0 : ((n > TOPK) ? TOPK : n);   // defensive clamp
    float cur = (inc0[row] || n == 0) ? 0.f : -3.402823466e38f;
    const float pi  = P[(size_t)row*DM + t];
    const float bb3 = b3[t];
    const float bb4 = b4[t];
    for (int k = 0; k < n; ++k) {
        int j = idxs[row*TOPK + k];
        j = (j < 0) ? 0 : ((j >= MROWS) ? MROWS-1 : j);  // defensive clamp
        u[t] = fmaxf(pi - P[(size_t)j*DM + t] + bb3, 0.f);
        __syncthreads();
        float acc = bb4;
        for (int k2 = 0; k2 < DM; k2 += 4) {
            const float4 uu = *(const float4*)&u[k2];
            acc += uu.x * W4[(k2+0)*DM + t]
                 + uu.y * W4[(k2+1)*DM + t]
                 + uu.z * W4[(k2+2)*DM + t]
                 + uu.w * W4[(k2+3)*DM + t];
        }
        cur = fmaxf(cur, acc);
        __syncthreads();
    }
    CMAX[(size_t)row*DM + t] = cur;
}

// ---------------- final: out = tgt + relu(CMAX @ W5 + b5) * (1 - seed) ------
__global__ __launch_bounds__(256) void gemm_final_k(
    const float* __restrict__ A, const float* __restrict__ W,
    const float* __restrict__ bias, const float* __restrict__ tgt,
    const float* __restrict__ seed, float* __restrict__ out)
{
    __shared__ __align__(16) float As[16][DM];
    const int t  = threadIdx.x;
    const int r0 = blockIdx.x * 16;
    for (int e = t; e < 16*DM; e += 256)
        As[e >> 8][e & 255] = A[(size_t)r0*DM + e];
    __syncthreads();
    float acc[16];
    #pragma unroll
    for (int r = 0; r < 16; ++r) acc[r] = 0.f;
    for (int k = 0; k < DM; k += 4) {
        const float w0 = W[(k+0)*DM + t];
        const float w1 = W[(k+1)*DM + t];
        const float w2 = W[(k+2)*DM + t];
        const float w3 = W[(k+3)*DM + t];
        #pragma unroll
        for (int r = 0; r < 16; ++r) {
            const float4 a = *(const float4*)&As[r][k];
            acc[r] += a.x*w0 + a.y*w1 + a.z*w2 + a.w*w3;
        }
    }
    const float bb = bias[t];
    #pragma unroll
    for (int r = 0; r < 16; ++r) {
        const int row = r0 + r;
        const float neg = 1.f - seed[row];
        const float v = fmaxf(acc[r] + bb, 0.f) * neg;
        out[(size_t)row*DM + t] = tgt[(size_t)row*DM + t] + v;
    }
}

extern "C" void kernel_launch(void* const* d_in, const int* in_sizes, int n_in,
                              void* d_out, int out_size, void* d_ws, size_t ws_size,
                              hipStream_t stream)
{
    (void)in_sizes; (void)n_in; (void)out_size; (void)ws_size;
    const float* tgt   = (const float*)d_in[0];
    const float* seed  = (const float*)d_in[1];
    const float* boxes = (const float*)d_in[2];
    const float* W1 = (const float*)d_in[3];
    const float* b1 = (const float*)d_in[4];
    const float* W2 = (const float*)d_in[5];
    const float* b2 = (const float*)d_in[6];
    const float* g2 = (const float*)d_in[7];
    const float* be2= (const float*)d_in[8];
    const float* W3 = (const float*)d_in[9];
    const float* b3 = (const float*)d_in[10];
    const float* W4 = (const float*)d_in[11];
    const float* b4 = (const float*)d_in[12];
    const float* W5 = (const float*)d_in[13];
    const float* b5 = (const float*)d_in[14];
    (void)g2; (void)be2;

    float* out_tgt  = (float*)d_out;                     // 8*1000*256 f32
    float* out_attn = out_tgt + (size_t)MROWS * DM;      // 8*1000*1000 f32 (bool as 0/1)

    // Workspace: 2 f32 row-buffers (8.192 MB each) + 0.36 MB metadata = 16.75 MB.
    // Buffer lifetimes:  B1: H -> ID -> CMAX     B2: Y -> P
    char* ws  = (char*)d_ws;
    float* B1 = (float*)ws;
    float* B2 = (float*)(ws + (size_t)MROWS*DM*4);
    int* cnt  = (int*)(ws + (size_t)MROWS*DM*8);
    int* inc0 = cnt + MROWS;
    int* idxs = inc0 + MROWS;

    iou_topk_k<<<MROWS, 256, 0, stream>>>(boxes, seed, out_attn, cnt, inc0, idxs);
    gemm_k<1><<<MROWS/16, 256, 0, stream>>>(tgt, W1, b1, B1);      // B1 = H = relu(tgt@W1+b1)
    gemm_k<0><<<MROWS/16, 256, 0, stream>>>(B1, W2, b2, B2);       // B2 = Y = H@W2+b2
    ln_k<<<MROWS/4, 256, 0, stream>>>(B2, g2, be2, B1);            // B1 = ID = LN(Y)
    gemm_k<0><<<MROWS/16, 256, 0, stream>>>(B1, W3, nullptr, B2);  // B2 = P = ID@W3
    pairs_k<<<MROWS, 256, 0, stream>>>(B2, b3, W4, b4, cnt, inc0, idxs, B1);  // B1 = CMAX
    gemm_final_k<<<MROWS/16, 256, 0, stream>>>(B1, W5, b5, tgt, seed, out_tgt);
}

// Round 4
// 159.307 us; speedup vs baseline: 1.8178x; 1.8178x over previous
//
#include <hip/hip_runtime.h>
#include <hip/hip_bf16.h>

#define BSZ   8
#define NQ    1000
#define DM    256
#define MROWS (BSZ*NQ)
#define TOPK  10

typedef __attribute__((ext_vector_type(8))) short short8;
typedef __attribute__((ext_vector_type(4))) float f32x4;
typedef unsigned short u16;

static __device__ __forceinline__ float b2f(u16 u) {
    unsigned int x = ((unsigned int)u) << 16;
    return __uint_as_float(x);
}
static __device__ __forceinline__ u16 f2b(float f) {
    __hip_bfloat16 h = __float2bfloat16(f);   // RNE cvt
    return *(u16*)&h;
}

// ---------------- IoU + attn_mask + top-k candidate selection ----------------
// Exact f32 path (contract off) — matches numpy reference bit-exactly on the
// >=0.5 comparisons, so attn_mask and the discrete top-k selection are exact.
__global__ __launch_bounds__(256) void iou_topk_k(
    const float* __restrict__ boxes, const float* __restrict__ seed,
    float* __restrict__ attn, int* __restrict__ cnt, int* __restrict__ inc0,
    int* __restrict__ idxs)
{
#pragma clang fp contract(off)
    __shared__ float sv[NQ];
    __shared__ int   sj[NQ];
    __shared__ int   scount;
    const int t   = threadIdx.x;
    const int row = blockIdx.x;          // b*NQ + i
    const int b   = row / NQ;
    if (t == 0) scount = 0;

    const float* bi = boxes + (size_t)row * 4;
    const float icx = bi[0], icy = bi[1], iw = bi[2], ih = bi[3];
    const float ix0 = icx - 0.5f*iw, iy0 = icy - 0.5f*ih;
    const float ix1 = icx + 0.5f*iw, iy1 = icy + 0.5f*ih;
    const float area_i = (ix1-ix0)*(iy1-iy0);
    const float neg_i  = 1.f - seed[row];
    __syncthreads();

    float* arow = attn + (size_t)row * NQ;
    for (int j = t; j < NQ; j += 256) {
        const float* bj = boxes + (size_t)(b*NQ + j) * 4;
        const float cx = bj[0], cy = bj[1], w = bj[2], h = bj[3];
        const float x0 = cx - 0.5f*w, y0 = cy - 0.5f*h;
        const float x1 = cx + 0.5f*w, y1 = cy + 0.5f*h;
        const float area_j = (x1-x0)*(y1-y0);
        const float ltx = fmaxf(ix0, x0), lty = fmaxf(iy0, y0);
        const float rbx = fminf(ix1, x1), rby = fminf(iy1, y1);
        const float wx = fmaxf(rbx-ltx, 0.f), wy = fmaxf(rby-lty, 0.f);
        const float inter = wx*wy;
        const float uni = (area_i + area_j) - inter;
        const float iou = inter / uni;
        arow[j] = (iou >= 0.5f) ? 1.0f : 0.0f;
        const float ov = (iou * seed[b*NQ + j]) * neg_i;  // exact: seed,neg in {0,1}
        if (ov >= 0.5f) {
            const int p = atomicAdd(&scount, 1);
            if (p < NQ) { sv[p] = ov; sj[p] = j; }
        }
    }
    __syncthreads();

    if (t == 0) {
        const int n = scount;
        inc0[row] = (n < TOPK) ? 1 : 0;
        if (n <= TOPK) {
            cnt[row] = n;
            for (int k = 0; k < n; ++k) idxs[row*TOPK + k] = b*NQ + sj[k];
        } else {
            float bv[TOPK]; int bj[TOPK];
            #pragma unroll
            for (int k = 0; k < TOPK; ++k) { bv[k] = -1.f; bj[k] = 0x7fffffff; }
            for (int e = 0; e < n; ++e) {
                const float v = sv[e]; const int j = sj[e];
                int w = 0;
                #pragma unroll
                for (int k = 1; k < TOPK; ++k)
                    if (bv[k] < bv[w] || (bv[k] == bv[w] && bj[k] > bj[w])) w = k;
                if (v > bv[w] || (v == bv[w] && j < bj[w])) { bv[w] = v; bj[w] = j; }
            }
            cnt[row] = TOPK;
            for (int k = 0; k < TOPK; ++k) idxs[row*TOPK + k] = b*NQ + bj[k];
        }
    }
}

// ---------------- weight prep: W[k][n] f32 -> WT[n][k] bf16 ------------------
__global__ __launch_bounds__(256) void prep_w_k(
    const float* __restrict__ W1, const float* __restrict__ W2,
    const float* __restrict__ W3, const float* __restrict__ W4,
    const float* __restrict__ W5, u16* __restrict__ WT)
{
    const int m = blockIdx.y;
    const float* W = (m == 0) ? W1 : (m == 1) ? W2 : (m == 2) ? W3 : (m == 3) ? W4 : W5;
    u16* D = WT + (size_t)m * DM * DM;
    const int t  = threadIdx.x;          // n
    const int kb = blockIdx.x * 16;
    u16 tmp[16];
    #pragma unroll
    for (int kk = 0; kk < 16; ++kk)
        tmp[kk] = f2b(W[(size_t)(kb+kk)*DM + t]);   // coalesced read
    #pragma unroll
    for (int kk = 0; kk < 16; ++kk)
        D[(size_t)t*DM + kb + kk] = tmp[kk];        // 32B contiguous per thread
}

// ---------------- tgt f32 -> bf16 ----------------
__global__ __launch_bounds__(256) void cvt_k(const float* __restrict__ src, u16* __restrict__ dst)
{
    const int i = (blockIdx.x * 256 + threadIdx.x) * 4;
    const float4 v = *(const float4*)&src[i];
    dst[i+0] = f2b(v.x); dst[i+1] = f2b(v.y); dst[i+2] = f2b(v.z); dst[i+3] = f2b(v.w);
}

// ---------------- MFMA GEMM: Out[M,256] = act(A_bf16 @ W + bias) -------------
// 16 rows per block (grid 500). A tile staged in LDS; WT (bf16, [n][k]) staged
// in 64-K chunks. 32 MFMA (16x16x32) per wave. Epilogue variants via template.
template<int RELU, int OUT_BF16, int FINAL>
__global__ __launch_bounds__(256) void mfma_gemm_k(
    const u16* __restrict__ A, const u16* __restrict__ WT,
    const float* __restrict__ bias, void* __restrict__ Out,
    const float* __restrict__ tgt, const float* __restrict__ seed)
{
    __shared__ __align__(16) u16 A_lds[16][264];   // +8 pad: bank spread
    __shared__ __align__(16) u16 W_lds[256][72];   // 64-K chunk, +8 pad
    const int t = threadIdx.x, r0 = blockIdx.x * 16;
    const int lane = t & 63, wave = t >> 6;
    const int m = lane & 15, quad = lane >> 4;

    #pragma unroll
    for (int it = 0; it < 2; ++it) {
        const int f = it*2048 + t*8, r = f >> 8, c = f & 255;
        *(uint4*)&A_lds[r][c] = *(const uint4*)&A[(size_t)(r0+r)*DM + c];
    }
    f32x4 acc[4];
    #pragma unroll
    for (int nt = 0; nt < 4; ++nt)
        #pragma unroll
        for (int i = 0; i < 4; ++i) acc[nt][i] = 0.f;

    for (int kc = 0; kc < 4; ++kc) {
        __syncthreads();   // A staged (first iter) / W_lds free (later iters)
        #pragma unroll
        for (int pass = 0; pass < 8; ++pass) {
            const int n = pass*32 + (t >> 3), ko = (t & 7) * 8;
            *(uint4*)&W_lds[n][ko] = *(const uint4*)&WT[(size_t)n*DM + kc*64 + ko];
        }
        __syncthreads();
        #pragma unroll
        for (int ks = 0; ks < 2; ++ks) {
            const short8 a = *(const short8*)&A_lds[m][kc*64 + ks*32 + quad*8];
            #pragma unroll
            for (int nt = 0; nt < 4; ++nt) {
                const int n = wave*64 + nt*16 + m;
                const short8 b = *(const short8*)&W_lds[n][ks*32 + quad*8];
                acc[nt] = __builtin_amdgcn_mfma_f32_16x16x32_bf16(a, b, acc[nt], 0, 0, 0);
            }
        }
    }
    // epilogue: D element (row = quad*4+reg, col = lane&15) per 16x16 tile
    #pragma unroll
    for (int nt = 0; nt < 4; ++nt) {
        const int n = wave*64 + nt*16 + m;
        const float bb = bias ? bias[n] : 0.f;
        #pragma unroll
        for (int reg = 0; reg < 4; ++reg) {
            const int R = r0 + quad*4 + reg;
            float v = acc[nt][reg] + bb;
            if (RELU) v = fmaxf(v, 0.f);
            if (FINAL) v = tgt[(size_t)R*DM + n] + fmaxf(v, 0.f) * (1.f - seed[R]);
            if (OUT_BF16) ((u16*)Out)[(size_t)R*DM + n] = f2b(v);
            else          ((float*)Out)[(size_t)R*DM + n] = v;
        }
    }
}

// ---------------- LayerNorm (bf16 in/out, f32 math): one wave per row --------
__global__ __launch_bounds__(256) void ln_k(
    const u16* __restrict__ Y, const float* __restrict__ g,
    const float* __restrict__ be, u16* __restrict__ ID)
{
    const int wave = threadIdx.x >> 6;
    const int lane = threadIdx.x & 63;
    const int row  = blockIdx.x * 4 + wave;
    const u16* y = Y + (size_t)row * DM;
    float x[4];
    #pragma unroll
    for (int i = 0; i < 4; ++i) x[i] = b2f(y[lane + 64*i]);
    float s = x[0]+x[1]+x[2]+x[3];
    float q = x[0]*x[0]+x[1]*x[1]+x[2]*x[2]+x[3]*x[3];
    #pragma unroll
    for (int off = 32; off; off >>= 1) {
        s += __shfl_down(s, off, 64);
        q += __shfl_down(q, off, 64);
    }
    s = __shfl(s, 0, 64);
    q = __shfl(q, 0, 64);
    const float mn  = s * (1.f/DM);
    const float vr  = q * (1.f/DM) - mn*mn;
    const float inv = rsqrtf(vr + 1e-5f);
    u16* o = ID + (size_t)row * DM;
    #pragma unroll
    for (int i = 0; i < 4; ++i) {
        const int c = lane + 64*i;
        o[c] = f2b((x[i]-mn)*inv*g[c] + be[c]);
    }
}

// ---------------- pairs via MFMA: 16 rows/block, chunked pair GEMM -----------
// Per block: gather active pairs (<=160), per 16-pair chunk build
// U = relu(P_i - P_j + b3) in LDS (bf16), MFMA U @ W4T, fold D into per-row
// running max in LDS, then emit CMAX (bf16).
__global__ __launch_bounds__(256) void pairs_mfma_k(
    const u16* __restrict__ P, const u16* __restrict__ W4T,
    const float* __restrict__ b3, const float* __restrict__ b4,
    const int* __restrict__ cnt, const int* __restrict__ inc0,
    const int* __restrict__ idxs, u16* __restrict__ CMAX)
{
    __shared__ __align__(16) u16 U[16][264];
    __shared__ __align__(16) u16 W_lds[256][72];    // overlaid with D after MFMA
    __shared__ float cm[16][264];
    __shared__ int pl_rl[176], pl_j[176];
    __shared__ int sInc[16];
    __shared__ int np;
    const int t = threadIdx.x, r0 = blockIdx.x * 16;
    const int lane = t & 63, wave = t >> 6;
    const int m = lane & 15, quad = lane >> 4;

    if (t == 0) np = 0;
    __syncthreads();
    if (t < 16) {
        const int r = r0 + t;
        int c = cnt[r];
        c = (c < 0) ? 0 : ((c > TOPK) ? TOPK : c);
        sInc[t] = inc0[r];
        const int base = atomicAdd(&np, c);
        for (int k = 0; k < c; ++k) {
            pl_rl[base + k] = t;
            int j = idxs[r*TOPK + k];
            j = (j < 0) ? 0 : ((j >= MROWS) ? MROWS-1 : j);
            pl_j[base + k] = j;
        }
    }
    __syncthreads();
    const int npairs = np;
    #pragma unroll
    for (int rl = 0; rl < 16; ++rl)
        cm[rl][t] = sInc[rl] ? 0.f : -3.402823466e38f;

    const float bb3 = b3[t];
    float* Dl = (float*)&W_lds[0][0];   // D[16][264] f32 (16.9KB <= 36.9KB)

    for (int pc = 0; pc*16 < npairs; ++pc) {
        // build U chunk (thread t owns col t)
        #pragma unroll
        for (int p = 0; p < 16; ++p) {
            const int pr = pc*16 + p;
            u16 uv = 0;
            if (pr < npairs) {
                const int i = r0 + pl_rl[pr];
                const int j = pl_j[pr];
                const float u = fmaxf(b2f(P[(size_t)i*DM + t]) - b2f(P[(size_t)j*DM + t]) + bb3, 0.f);
                uv = f2b(u);
            }
            U[p][t] = uv;
        }
        f32x4 acc[4];
        #pragma unroll
        for (int nt = 0; nt < 4; ++nt)
            #pragma unroll
            for (int i = 0; i < 4; ++i) acc[nt][i] = 0.f;
        for (int kc = 0; kc < 4; ++kc) {
            __syncthreads();   // U built / D folds done / W_lds free
            #pragma unroll
            for (int pass = 0; pass < 8; ++pass) {
                const int n = pass*32 + (t >> 3), ko = (t & 7) * 8;
                *(uint4*)&W_lds[n][ko] = *(const uint4*)&W4T[(size_t)n*DM + kc*64 + ko];
            }
            __syncthreads();
            #pragma unroll
            for (int ks = 0; ks < 2; ++ks) {
                const short8 a = *(const short8*)&U[m][kc*64 + ks*32 + quad*8];
                #pragma unroll
                for (int nt = 0; nt < 4; ++nt) {
                    const int n = wave*64 + nt*16 + m;
                    const short8 b = *(const short8*)&W_lds[n][ks*32 + quad*8];
                    acc[nt] = __builtin_amdgcn_mfma_f32_16x16x32_bf16(a, b, acc[nt], 0, 0, 0);
                }
            }
        }
        __syncthreads();       // all waves done reading W_lds -> reuse as D
        #pragma unroll
        for (int nt = 0; nt < 4; ++nt) {
            const int n = wave*64 + nt*16 + m;
            const float bb4 = b4[n];
            #pragma unroll
            for (int reg = 0; reg < 4; ++reg)
                Dl[(quad*4 + reg)*264 + n] = acc[nt][reg] + bb4;
        }
        __syncthreads();
        // fold chunk into per-row max (thread t owns col t; no races)
        #pragma unroll
        for (int p = 0; p < 16; ++p) {
            const int pr = pc*16 + p;
            if (pr < npairs) {
                const int rl = pl_rl[pr];
                cm[rl][t] = fmaxf(cm[rl][t], Dl[p*264 + t]);
            }
        }
    }
    #pragma unroll
    for (int rl = 0; rl < 16; ++rl)
        CMAX[(size_t)(r0 + rl)*DM + t] = f2b(cm[rl][t]);
}

extern "C" void kernel_launch(void* const* d_in, const int* in_sizes, int n_in,
                              void* d_out, int out_size, void* d_ws, size_t ws_size,
                              hipStream_t stream)
{
    (void)in_sizes; (void)n_in; (void)out_size; (void)ws_size;
    const float* tgt   = (const float*)d_in[0];
    const float* seed  = (const float*)d_in[1];
    const float* boxes = (const float*)d_in[2];
    const float* W1 = (const float*)d_in[3];
    const float* b1 = (const float*)d_in[4];
    const float* W2 = (const float*)d_in[5];
    const float* b2 = (const float*)d_in[6];
    const float* g2 = (const float*)d_in[7];
    const float* be2= (const float*)d_in[8];
    const float* W3 = (const float*)d_in[9];
    const float* b3 = (const float*)d_in[10];
    const float* W4 = (const float*)d_in[11];
    const float* b4 = (const float*)d_in[12];
    const float* W5 = (const float*)d_in[13];
    const float* b5 = (const float*)d_in[14];

    float* out_tgt  = (float*)d_out;                     // 8*1000*256 f32
    float* out_attn = out_tgt + (size_t)MROWS * DM;      // 8*1000*1000 f32

    // ws: WT (5x128KB bf16) | slotA 4MB bf16 | slotB 4MB bf16 | meta 384KB  = ~9MB
    //   slotA: tgt_bf -> Y_bf -> P_bf        slotB: H_bf -> ID_bf -> CMAX_bf
    u16* WT    = (u16*)d_ws;
    u16* slotA = WT + (size_t)5*DM*DM;
    u16* slotB = slotA + (size_t)MROWS*DM;
    int* cnt   = (int*)(slotB + (size_t)MROWS*DM);
    int* inc0  = cnt + MROWS;
    int* idxs  = inc0 + MROWS;
    u16* W1T = WT;
    u16* W2T = WT + (size_t)1*DM*DM;
    u16* W3T = WT + (size_t)2*DM*DM;
    u16* W4T = WT + (size_t)3*DM*DM;
    u16* W5T = WT + (size_t)4*DM*DM;

    prep_w_k<<<dim3(16,5), 256, 0, stream>>>(W1, W2, W3, W4, W5, WT);
    cvt_k<<<MROWS*DM/1024, 256, 0, stream>>>(tgt, slotA);                       // tgt_bf
    iou_topk_k<<<MROWS, 256, 0, stream>>>(boxes, seed, out_attn, cnt, inc0, idxs);
    mfma_gemm_k<1,1,0><<<MROWS/16, 256, 0, stream>>>(slotA, W1T, b1, slotB, nullptr, nullptr); // H
    mfma_gemm_k<0,1,0><<<MROWS/16, 256, 0, stream>>>(slotB, W2T, b2, slotA, nullptr, nullptr); // Y
    ln_k<<<MROWS/4, 256, 0, stream>>>(slotA, g2, be2, slotB);                   // ID
    mfma_gemm_k<0,1,0><<<MROWS/16, 256, 0, stream>>>(slotB, W3T, nullptr, slotA, nullptr, nullptr); // P
    pairs_mfma_k<<<MROWS/16, 256, 0, stream>>>(slotA, W4T, b3, b4, cnt, inc0, idxs, slotB);    // CMAX
    mfma_gemm_k<0,0,1><<<MROWS/16, 256, 0, stream>>>(slotB, W5T, b5, out_tgt, tgt, seed);      // out
}

// Round 5
// 142.416 us; speedup vs baseline: 2.0334x; 1.1186x over previous
//
#include <hip/hip_runtime.h>
#include <hip/hip_bf16.h>

#define BSZ   8
#define NQ    1000
#define DM    256
#define MROWS (BSZ*NQ)
#define TOPK  10

typedef __attribute__((ext_vector_type(8))) short short8;
typedef __attribute__((ext_vector_type(4))) float f32x4;
typedef unsigned short u16;

static __device__ __forceinline__ float b2f(u16 u) {
    unsigned int x = ((unsigned int)u) << 16;
    return __uint_as_float(x);
}
static __device__ __forceinline__ u16 f2b(float f) {
    __hip_bfloat16 h = __float2bfloat16(f);   // RNE cvt
    return *(u16*)&h;
}

// ============ K1: weight prep (blocks 0..79) + IoU/top-k (blocks 80..8079) ===
// IoU path is exact f32 (contract off) — matches the numpy f32 reference
// bit-exactly on every >=0.5 comparison, so attn_mask and the discrete top-k
// selection are exact. Weight-prep blocks transpose W[k][n] f32 -> WT[n][k]
// bf16 for the MFMA kernels.
__global__ __launch_bounds__(256) void prep_iou_k(
    const float* __restrict__ boxes, const float* __restrict__ seed,
    const float* __restrict__ W1, const float* __restrict__ W2,
    const float* __restrict__ W3, const float* __restrict__ W4,
    const float* __restrict__ W5, u16* __restrict__ WT,
    float* __restrict__ attn, int* __restrict__ cnt,
    int* __restrict__ inc0, int* __restrict__ idxs)
{
#pragma clang fp contract(off)
    if (blockIdx.x < 80) {
        const int m  = blockIdx.x >> 4;
        const int kb = (blockIdx.x & 15) * 16;
        const float* W = (m==0)?W1:(m==1)?W2:(m==2)?W3:(m==3)?W4:W5;
        u16* D = WT + (size_t)m * DM * DM;
        const int t = threadIdx.x;           // n
        u16 tmp[16];
        #pragma unroll
        for (int kk = 0; kk < 16; ++kk)
            tmp[kk] = f2b(W[(size_t)(kb+kk)*DM + t]);    // coalesced read
        #pragma unroll
        for (int kk = 0; kk < 16; ++kk)
            D[(size_t)t*DM + kb + kk] = tmp[kk];         // 32B contiguous/thread
        return;
    }

    __shared__ float sv[NQ];
    __shared__ int   sj[NQ];
    __shared__ int   scount;
    const int t   = threadIdx.x;
    const int row = blockIdx.x - 80;     // b*NQ + i
    const int b   = row / NQ;
    if (t == 0) scount = 0;

    const float* bi = boxes + (size_t)row * 4;
    const float icx = bi[0], icy = bi[1], iw = bi[2], ih = bi[3];
    const float ix0 = icx - 0.5f*iw, iy0 = icy - 0.5f*ih;
    const float ix1 = icx + 0.5f*iw, iy1 = icy + 0.5f*ih;
    const float area_i = (ix1-ix0)*(iy1-iy0);
    const float neg_i  = 1.f - seed[row];
    __syncthreads();

    float* arow = attn + (size_t)row * NQ;
    for (int j = t; j < NQ; j += 256) {
        const float* bj = boxes + (size_t)(b*NQ + j) * 4;
        const float cx = bj[0], cy = bj[1], w = bj[2], h = bj[3];
        const float x0 = cx - 0.5f*w, y0 = cy - 0.5f*h;
        const float x1 = cx + 0.5f*w, y1 = cy + 0.5f*h;
        const float area_j = (x1-x0)*(y1-y0);
        const float ltx = fmaxf(ix0, x0), lty = fmaxf(iy0, y0);
        const float rbx = fminf(ix1, x1), rby = fminf(iy1, y1);
        const float wx = fmaxf(rbx-ltx, 0.f), wy = fmaxf(rby-lty, 0.f);
        const float inter = wx*wy;
        const float uni = (area_i + area_j) - inter;
        const float iou = inter / uni;
        arow[j] = (iou >= 0.5f) ? 1.0f : 0.0f;
        const float ov = (iou * seed[b*NQ + j]) * neg_i;  // exact: seed,neg in {0,1}
        if (ov >= 0.5f) {
            const int p = atomicAdd(&scount, 1);
            if (p < NQ) { sv[p] = ov; sj[p] = j; }
        }
    }
    __syncthreads();

    if (t == 0) {
        const int n = scount;
        inc0[row] = (n < TOPK) ? 1 : 0;
        if (n <= TOPK) {
            cnt[row] = n;
            for (int k = 0; k < n; ++k) idxs[row*TOPK + k] = b*NQ + sj[k];
        } else {
            float bv[TOPK]; int bj[TOPK];
            #pragma unroll
            for (int k = 0; k < TOPK; ++k) { bv[k] = -1.f; bj[k] = 0x7fffffff; }
            for (int e = 0; e < n; ++e) {
                const float v = sv[e]; const int j = sj[e];
                int w = 0;
                #pragma unroll
                for (int k = 1; k < TOPK; ++k)
                    if (bv[k] < bv[w] || (bv[k] == bv[w] && bj[k] > bj[w])) w = k;
                if (v > bv[w] || (v == bv[w] && j < bj[w])) { bv[w] = v; bj[w] = j; }
            }
            cnt[row] = TOPK;
            for (int k = 0; k < TOPK; ++k) idxs[row*TOPK + k] = b*NQ + bj[k];
        }
    }
}

// ============ shared 16x256x256 block-GEMM (MFMA 16x16x32 bf16) ==============
// A is a [16][264] bf16 LDS tile; WT is [n][k] bf16 global, streamed through
// W_lds in 64-K chunks. Epilogue variants:
//   0: relu(acc+bias) -> OutL    1: acc+bias -> OutL
//   2: acc -> OutG (bf16 global) 3: final residual -> OutF (f32 global)
template<int EPI>
static __device__ __forceinline__ void block_gemm256(
    const u16 (*__restrict__ A)[264], const u16* __restrict__ WT,
    const float* __restrict__ bias, u16 (*__restrict__ OutL)[264],
    u16* __restrict__ OutG, float* __restrict__ OutF,
    const float* __restrict__ tgt, const float* __restrict__ seed,
    int r0, u16 (*__restrict__ W_lds)[72], int t)
{
    const int lane = t & 63, wave = t >> 6;
    const int m = lane & 15, quad = lane >> 4;
    f32x4 acc[4];
    #pragma unroll
    for (int nt = 0; nt < 4; ++nt)
        #pragma unroll
        for (int i = 0; i < 4; ++i) acc[nt][i] = 0.f;
    for (int kc = 0; kc < 4; ++kc) {
        __syncthreads();   // A ready / W_lds & prior-A free for reuse
        #pragma unroll
        for (int pass = 0; pass < 8; ++pass) {
            const int n = pass*32 + (t >> 3), ko = (t & 7) * 8;
            *(uint4*)&W_lds[n][ko] = *(const uint4*)&WT[(size_t)n*DM + kc*64 + ko];
        }
        __syncthreads();
        #pragma unroll
        for (int ks = 0; ks < 2; ++ks) {
            const short8 a = *(const short8*)&A[m][kc*64 + ks*32 + quad*8];
            #pragma unroll
            for (int nt = 0; nt < 4; ++nt) {
                const int n = wave*64 + nt*16 + m;
                const short8 b = *(const short8*)&W_lds[n][ks*32 + quad*8];
                acc[nt] = __builtin_amdgcn_mfma_f32_16x16x32_bf16(a, b, acc[nt], 0, 0, 0);
            }
        }
    }
    // C/D: row = quad*4+reg, col = wave*64+nt*16+m
    #pragma unroll
    for (int nt = 0; nt < 4; ++nt) {
        const int n = wave*64 + nt*16 + m;
        const float bb = bias ? bias[n] : 0.f;
        #pragma unroll
        for (int reg = 0; reg < 4; ++reg) {
            const int rl = quad*4 + reg;
            float v = acc[nt][reg] + bb;
            if (EPI == 0) OutL[rl][n] = f2b(fmaxf(v, 0.f));
            if (EPI == 1) OutL[rl][n] = f2b(v);
            if (EPI == 2) OutG[(size_t)(r0+rl)*DM + n] = f2b(v);
            if (EPI == 3) {
                const int R = r0 + rl;
                OutF[(size_t)R*DM + n] = tgt[(size_t)R*DM + n]
                                       + fmaxf(v, 0.f) * (1.f - seed[R]);
            }
        }
    }
}

// ============ K2: fused MLP chain  tgt -> H -> Y -> LN -> P ==================
__global__ __launch_bounds__(256) void mlp_k(
    const float* __restrict__ tgt, const u16* __restrict__ WT,
    const float* __restrict__ b1, const float* __restrict__ b2,
    const float* __restrict__ g2, const float* __restrict__ be2,
    u16* __restrict__ P)
{
    __shared__ __align__(16) u16 bufA[16][264];
    __shared__ __align__(16) u16 bufB[16][264];
    __shared__ __align__(16) u16 W_lds[256][72];
    const int t = threadIdx.x, r0 = blockIdx.x * 16;
    const int lane = t & 63, wave = t >> 6;

    // stage tgt f32 -> bufA bf16 (thread t: row t>>4, 16 cols from (t&15)*16)
    {
        const int r = t >> 4, c0 = (t & 15) * 16;
        const float* src = &tgt[(size_t)(r0 + r)*DM + c0];
        u16 h[16];
        #pragma unroll
        for (int q = 0; q < 4; ++q) {
            const float4 f = *(const float4*)&src[q*4];
            h[q*4+0] = f2b(f.x); h[q*4+1] = f2b(f.y);
            h[q*4+2] = f2b(f.z); h[q*4+3] = f2b(f.w);
        }
        *(uint4*)&bufA[r][c0]     = *(uint4*)&h[0];
        *(uint4*)&bufA[r][c0 + 8] = *(uint4*)&h[8];
    }
    const u16* W1T = WT;
    const u16* W2T = WT + (size_t)1*DM*DM;
    const u16* W3T = WT + (size_t)2*DM*DM;

    block_gemm256<0>(bufA, W1T, b1, bufB, nullptr, nullptr, nullptr, nullptr, r0, W_lds, t); // H
    block_gemm256<1>(bufB, W2T, b2, bufA, nullptr, nullptr, nullptr, nullptr, r0, W_lds, t); // Y
    __syncthreads();
    // LayerNorm rows in LDS: wave w handles rows 4w..4w+3
    for (int rr = 0; rr < 4; ++rr) {
        const int row = wave*4 + rr;
        float x[4];
        #pragma unroll
        for (int i = 0; i < 4; ++i) x[i] = b2f(bufA[row][lane + 64*i]);
        float s = x[0]+x[1]+x[2]+x[3];
        float q = x[0]*x[0]+x[1]*x[1]+x[2]*x[2]+x[3]*x[3];
        #pragma unroll
        for (int off = 32; off; off >>= 1) {
            s += __shfl_down(s, off, 64);
            q += __shfl_down(q, off, 64);
        }
        s = __shfl(s, 0, 64); q = __shfl(q, 0, 64);
        const float mn  = s * (1.f/DM);
        const float vr  = q * (1.f/DM) - mn*mn;
        const float inv = rsqrtf(vr + 1e-5f);
        #pragma unroll
        for (int i = 0; i < 4; ++i) {
            const int c = lane + 64*i;
            bufA[row][c] = f2b((x[i]-mn)*inv*g2[c] + be2[c]);
        }
    }
    // gemm3's leading __syncthreads covers the LN writes
    block_gemm256<2>(bufA, W3T, nullptr, nullptr, P, nullptr, nullptr, nullptr, r0, W_lds, t);
}

// ============ K3: pairs (MFMA chunks + masked max) + final GEMM + residual ===
__global__ __launch_bounds__(256) void pairs_final_k(
    const u16* __restrict__ P, const u16* __restrict__ WT,
    const float* __restrict__ b3, const float* __restrict__ b4,
    const float* __restrict__ b5,
    const int* __restrict__ cnt, const int* __restrict__ inc0,
    const int* __restrict__ idxs,
    const float* __restrict__ tgt, const float* __restrict__ seed,
    float* __restrict__ out)
{
    __shared__ __align__(16) u16 U[16][264];
    __shared__ __align__(16) u16 W_lds[256][72];    // overlaid with f32 D after MFMA
    __shared__ float cm[16][264];
    __shared__ int pl_rl[176], pl_j[176];
    __shared__ int sInc[16];
    __shared__ int np;
    const int t = threadIdx.x, r0 = blockIdx.x * 16;
    const int lane = t & 63, wave = t >> 6;
    const int m = lane & 15, quad = lane >> 4;
    const u16* W4T = WT + (size_t)3*DM*DM;
    const u16* W5T = WT + (size_t)4*DM*DM;

    if (t == 0) np = 0;
    __syncthreads();
    if (t < 16) {
        const int r = r0 + t;
        int c = cnt[r];
        c = (c < 0) ? 0 : ((c > TOPK) ? TOPK : c);
        sInc[t] = inc0[r];
        const int base = atomicAdd(&np, c);
        for (int k = 0; k < c; ++k) {
            pl_rl[base + k] = t;
            int j = idxs[r*TOPK + k];
            j = (j < 0) ? 0 : ((j >= MROWS) ? MROWS-1 : j);
            pl_j[base + k] = j;
        }
    }
    __syncthreads();
    const int npairs = np;
    #pragma unroll
    for (int rl = 0; rl < 16; ++rl)
        cm[rl][t] = sInc[rl] ? 0.f : -3.402823466e38f;

    const float bb3 = b3[t];
    float* Dl = (float*)&W_lds[0][0];   // D[16][264] f32 (16.9KB <= 36.9KB)

    for (int pc = 0; pc*16 < npairs; ++pc) {
        #pragma unroll
        for (int p = 0; p < 16; ++p) {
            const int pr = pc*16 + p;
            u16 uv = 0;
            if (pr < npairs) {
                const int i = r0 + pl_rl[pr];
                const int j = pl_j[pr];
                const float u = fmaxf(b2f(P[(size_t)i*DM + t]) - b2f(P[(size_t)j*DM + t]) + bb3, 0.f);
                uv = f2b(u);
            }
            U[p][t] = uv;
        }
        f32x4 acc[4];
        #pragma unroll
        for (int nt = 0; nt < 4; ++nt)
            #pragma unroll
            for (int i = 0; i < 4; ++i) acc[nt][i] = 0.f;
        for (int kc = 0; kc < 4; ++kc) {
            __syncthreads();   // U built / D folds done / W_lds free
            #pragma unroll
            for (int pass = 0; pass < 8; ++pass) {
                const int n = pass*32 + (t >> 3), ko = (t & 7) * 8;
                *(uint4*)&W_lds[n][ko] = *(const uint4*)&W4T[(size_t)n*DM + kc*64 + ko];
            }
            __syncthreads();
            #pragma unroll
            for (int ks = 0; ks < 2; ++ks) {
                const short8 a = *(const short8*)&U[m][kc*64 + ks*32 + quad*8];
                #pragma unroll
                for (int nt = 0; nt < 4; ++nt) {
                    const int n = wave*64 + nt*16 + m;
                    const short8 b = *(const short8*)&W_lds[n][ks*32 + quad*8];
                    acc[nt] = __builtin_amdgcn_mfma_f32_16x16x32_bf16(a, b, acc[nt], 0, 0, 0);
                }
            }
        }
        __syncthreads();       // all U/W_lds reads done -> reuse W_lds as D
        #pragma unroll
        for (int nt = 0; nt < 4; ++nt) {
            const int n = wave*64 + nt*16 + m;
            const float bb4 = b4[n];
            #pragma unroll
            for (int reg = 0; reg < 4; ++reg)
                Dl[(quad*4 + reg)*264 + n] = acc[nt][reg] + bb4;
        }
        __syncthreads();
        #pragma unroll
        for (int p = 0; p < 16; ++p) {
            const int pr = pc*16 + p;
            if (pr < npairs) {
                const int rl = pl_rl[pr];
                cm[rl][t] = fmaxf(cm[rl][t], Dl[p*264 + t]);   // col t owned by t
            }
        }
    }
    // CMAX (cm column t is thread-private) -> bf16 A-tile; gemm's leading sync
    // guards the cross-thread reads.
    #pragma unroll
    for (int rl = 0; rl < 16; ++rl)
        U[rl][t] = f2b(cm[rl][t]);
    block_gemm256<3>(U, W5T, b5, nullptr, nullptr, out, tgt, seed, r0, W_lds, t);
}

extern "C" void kernel_launch(void* const* d_in, const int* in_sizes, int n_in,
                              void* d_out, int out_size, void* d_ws, size_t ws_size,
                              hipStream_t stream)
{
    (void)in_sizes; (void)n_in; (void)out_size; (void)ws_size;
    const float* tgt   = (const float*)d_in[0];
    const float* seed  = (const float*)d_in[1];
    const float* boxes = (const float*)d_in[2];
    const float* W1 = (const float*)d_in[3];
    const float* b1 = (const float*)d_in[4];
    const float* W2 = (const float*)d_in[5];
    const float* b2 = (const float*)d_in[6];
    const float* g2 = (const float*)d_in[7];
    const float* be2= (const float*)d_in[8];
    const float* W3 = (const float*)d_in[9];
    const float* b3 = (const float*)d_in[10];
    const float* W4 = (const float*)d_in[11];
    const float* b4 = (const float*)d_in[12];
    const float* W5 = (const float*)d_in[13];
    const float* b5 = (const float*)d_in[14];

    float* out_tgt  = (float*)d_out;                     // 8*1000*256 f32
    float* out_attn = out_tgt + (size_t)MROWS * DM;      // 8*1000*1000 f32

    // ws: WT (5 x 128KB bf16) | P (4MB bf16) | meta (~0.36MB)  ~= 5.1 MB
    u16* WT   = (u16*)d_ws;
    u16* P    = WT + (size_t)5*DM*DM;
    int* cnt  = (int*)(P + (size_t)MROWS*DM);
    int* inc0 = cnt + MROWS;
    int* idxs = inc0 + MROWS;

    prep_iou_k<<<80 + MROWS, 256, 0, stream>>>(boxes, seed, W1, W2, W3, W4, W5,
                                               WT, out_attn, cnt, inc0, idxs);
    mlp_k<<<MROWS/16, 256, 0, stream>>>(tgt, WT, b1, b2, g2, be2, P);
    pairs_final_k<<<MROWS/16, 256, 0, stream>>>(P, WT, b3, b4, b5, cnt, inc0, idxs,
                                                tgt, seed, out_tgt);
}